// Round 5
// baseline (174.139 us; speedup 1.0000x reference)
//
#include <hip/hip_runtime.h>

// N=100000, E=3200000, H=256, G=128.
// Pipeline (4 kernels): per-block dense histogram -> per-bucket scan ->
// scatter into fixed-capacity buckets -> fused LDS bucket-reduce + collapsed
// MLP f(a)=sum_k relu(a*Wl[k]+bl[k])*Wo[k] + graph mean-pool + epilogue
// (last-finishing block applies it via a device-scope ticket).
// Round-4 lessons: harness reset floor ~83us; kernel-node count and s2
// occupancy (25%) were the remaining levers. Zero global atomics in binning.

#define GMAX  128      // max graphs
#define HMAX  256      // max hidden dim
#define BS    256      // nodes per bucket (dst >> 8)
#define NBMAX 512      // max buckets (N <= 131072)
#define SG    1024     // blocks for s1/s2

// ---------------- main path ----------------

// S1: per-block dense histogram of dst buckets; cnt[blk][b] coalesced write.
__global__ __launch_bounds__(256) void s1_count(const int* __restrict__ ei,
                                                unsigned* __restrict__ cnt,
                                                int E, int NB, int QpB) {
  __shared__ unsigned h[NBMAX];
  int tid = threadIdx.x;
  for (int b = tid; b < NB; b += 256) h[b] = 0u;
  __syncthreads();
  int Q = E >> 2;
  int q0 = blockIdx.x * QpB;
  int q1 = min(q0 + QpB, Q);
  const int4* d4 = (const int4*)(ei + E);
  for (int q = q0 + tid; q < q1; q += 256) {
    int4 d = d4[q];
    atomicAdd(&h[d.x >> 8], 1u);
    atomicAdd(&h[d.y >> 8], 1u);
    atomicAdd(&h[d.z >> 8], 1u);
    atomicAdd(&h[d.w >> 8], 1u);
  }
  if (blockIdx.x == 0)   // tail edges (E % 4) counted by block 0
    for (int e = (Q << 2) + tid; e < E; e += 256)
      atomicAdd(&h[ei[E + e] >> 8], 1u);
  __syncthreads();
  for (int b = tid; b < NB; b += 256)
    cnt[(size_t)blockIdx.x * NBMAX + b] = h[b];
}

// Scan: block b scans the SG per-block counts of bucket b (strided gather,
// latency-tolerant), writes off[blk][b] (strided scatter) + tot[b].
// Block 0 also zeros gsum/gcnt/done.
__global__ __launch_bounds__(SG) void s_scan(const unsigned* __restrict__ cnt,
                                             unsigned* __restrict__ off,
                                             unsigned* __restrict__ tot,
                                             float* __restrict__ gsum,
                                             float* __restrict__ gcnt,
                                             unsigned* __restrict__ done) {
  __shared__ unsigned s[SG];
  int b = blockIdx.x, t = threadIdx.x;
  unsigned c = cnt[(size_t)t * NBMAX + b];
  s[t] = c;
  __syncthreads();
  for (int o = 1; o < SG; o <<= 1) {
    unsigned v = (t >= o) ? s[t - o] : 0u;
    __syncthreads();
    s[t] += v;
    __syncthreads();
  }
  off[(size_t)t * NBMAX + b] = s[t] - c;
  if (t == SG - 1) tot[b] = s[t];
  if (b == 0) {
    if (t < GMAX) { gsum[t] = 0.f; gcnt[t] = 0.f; }
    if (t == 0) done[0] = 0u;
  }
}

// S2: scatter edges into fixed-cap buckets (base = b*CAP) at precomputed
// offsets; only LDS rank atomics. pairs[slot] = (src<<8) | (dst & 255).
__global__ __launch_bounds__(256) void s2_scatter(const int* __restrict__ ei,
                                                  const unsigned* __restrict__ off,
                                                  unsigned* __restrict__ pairs,
                                                  int E, int NB, int QpB, int CAP) {
  __shared__ unsigned hb[NBMAX];    // my block's write base per bucket
  __shared__ unsigned rcur[NBMAX];  // local running rank
  int tid = threadIdx.x;
  for (int b = tid; b < NB; b += 256) {
    hb[b] = (unsigned)b * (unsigned)CAP + off[(size_t)blockIdx.x * NBMAX + b];
    rcur[b] = 0u;
  }
  __syncthreads();
  int Q = E >> 2;
  int q0 = blockIdx.x * QpB;
  int q1 = min(q0 + QpB, Q);
  const int4* s4 = (const int4*)ei;
  const int4* d4 = (const int4*)(ei + E);
  unsigned capu = (unsigned)CAP;
  for (int q = q0 + tid; q < q1; q += 256) {
    int4 s = s4[q];
    int4 d = d4[q];
    { int b = d.x >> 8; unsigned r = atomicAdd(&rcur[b], 1u);
      unsigned slot = hb[b] + r;
      if (slot < (unsigned)(b + 1) * capu)   // clamp: never corrupt neighbors
        pairs[slot] = ((unsigned)s.x << 8) | (unsigned)(d.x & 255); }
    { int b = d.y >> 8; unsigned r = atomicAdd(&rcur[b], 1u);
      unsigned slot = hb[b] + r;
      if (slot < (unsigned)(b + 1) * capu)
        pairs[slot] = ((unsigned)s.y << 8) | (unsigned)(d.y & 255); }
    { int b = d.z >> 8; unsigned r = atomicAdd(&rcur[b], 1u);
      unsigned slot = hb[b] + r;
      if (slot < (unsigned)(b + 1) * capu)
        pairs[slot] = ((unsigned)s.z << 8) | (unsigned)(d.z & 255); }
    { int b = d.w >> 8; unsigned r = atomicAdd(&rcur[b], 1u);
      unsigned slot = hb[b] + r;
      if (slot < (unsigned)(b + 1) * capu)
        pairs[slot] = ((unsigned)s.w << 8) | (unsigned)(d.w & 255); }
  }
  if (blockIdx.x == 0)   // tail edges, matching s1_count
    for (int e = (Q << 2) + tid; e < E; e += 256) {
      int d = ei[E + e], s = ei[e];
      int b = d >> 8; unsigned r = atomicAdd(&rcur[b], 1u);
      unsigned slot = hb[b] + r;
      if (slot < (unsigned)(b + 1) * capu)
        pairs[slot] = ((unsigned)s << 8) | (unsigned)(d & 255);
    }
}

// S3 (fused): bucket reduce in LDS -> per-node f(a) -> per-graph pooling;
// the last block to finish applies the final epilogue.
__global__ __launch_bounds__(256) void s3_reduce(
    const unsigned* __restrict__ pairs, const unsigned* __restrict__ tot,
    const float* __restrict__ x, const int* __restrict__ batch,
    const float* __restrict__ Wl, const float* __restrict__ bl,
    const float* __restrict__ Wo, const float* __restrict__ b_out,
    float* __restrict__ gsum, float* __restrict__ gcnt,
    unsigned* __restrict__ done, float* __restrict__ out,
    int N, int H, int G, int CAP) {
  __shared__ float acc[BS];
  __shared__ float sWl[HMAX], sbl[HMAX], sWo[HMAX];
  __shared__ float ls[GMAX], lc[GMAX];
  __shared__ unsigned ticket;
  int tid = threadIdx.x, b = blockIdx.x;
  acc[tid] = 0.f;
  if (tid < H) { sWl[tid] = Wl[tid]; sbl[tid] = bl[tid]; sWo[tid] = Wo[tid]; }
  if (tid < GMAX) { ls[tid] = 0.f; lc[tid] = 0.f; }
  __syncthreads();

  unsigned lo = (unsigned)b * (unsigned)CAP;
  unsigned cnt = min(tot[b], (unsigned)CAP);
  unsigned q4 = cnt >> 2;
  const uint4* p4 = (const uint4*)(pairs + lo);   // CAP%4==0 -> 16B aligned
  for (unsigned i = tid; i < q4; i += 256) {
    uint4 p = p4[i];
    atomicAdd(&acc[p.x & 255u], x[p.x >> 8]);
    atomicAdd(&acc[p.y & 255u], x[p.y >> 8]);
    atomicAdd(&acc[p.z & 255u], x[p.z >> 8]);
    atomicAdd(&acc[p.w & 255u], x[p.w >> 8]);
  }
  if (tid < (int)(cnt & 3u)) {
    unsigned p = pairs[lo + (q4 << 2) + tid];
    atomicAdd(&acc[p & 255u], x[p >> 8]);
  }
  __syncthreads();

  int node = b * BS + tid;
  if (node < N) {
    float a = acc[tid], f = 0.f;
#pragma unroll 8
    for (int k = 0; k < H; ++k) {
      float hh = fmaf(a, sWl[k], sbl[k]);
      f = fmaf(fmaxf(hh, 0.f), sWo[k], f);
    }
    int g = batch[node];
    atomicAdd(&ls[g], f);
    atomicAdd(&lc[g], 1.f);
  }
  __syncthreads();
  if (tid < GMAX && lc[tid] != 0.f) {
    atomicAdd(&gsum[tid], ls[tid]);   // device-scope
    atomicAdd(&gcnt[tid], lc[tid]);
  }
  // epilogue: last block to finish computes out[g]
  __threadfence();
  __syncthreads();
  if (tid == 0) ticket = atomicAdd(done, 1u);
  __syncthreads();
  if (ticket == gridDim.x - 1 && tid < G) {
    float s = __hip_atomic_load(&gsum[tid], __ATOMIC_RELAXED, __HIP_MEMORY_SCOPE_AGENT);
    float c = __hip_atomic_load(&gcnt[tid], __ATOMIC_RELAXED, __HIP_MEMORY_SCOPE_AGENT);
    out[tid] = fmaxf(s / fmaxf(c, 1.f) + b_out[0], 0.f);
  }
}

// ---------------- fallback path (small ws or oversized N) ----------------

__global__ __launch_bounds__(256) void fb_scatter(const int* __restrict__ ei,
                                                  const float* __restrict__ x,
                                                  float* __restrict__ agg, int E) {
  int t = blockIdx.x * blockDim.x + threadIdx.x;
  if (t < E) atomicAdd(&agg[ei[E + t]], x[ei[t]]);
}

__global__ __launch_bounds__(256) void fb_node(const float* __restrict__ agg,
                                               const int* __restrict__ batch,
                                               const float* __restrict__ Wl,
                                               const float* __restrict__ bl,
                                               const float* __restrict__ Wo,
                                               float* __restrict__ gsum,
                                               float* __restrict__ gcnt, int N, int H) {
  __shared__ float sWl[HMAX], sbl[HMAX], sWo[HMAX];
  __shared__ float ls[GMAX], lc[GMAX];
  int tid = threadIdx.x;
  if (tid < H) { sWl[tid] = Wl[tid]; sbl[tid] = bl[tid]; sWo[tid] = Wo[tid]; }
  if (tid < GMAX) { ls[tid] = 0.f; lc[tid] = 0.f; }
  __syncthreads();
  int i = blockIdx.x * blockDim.x + tid;
  if (i < N) {
    float a = agg[i], f = 0.f;
    for (int k = 0; k < H; ++k) {
      float hh = fmaf(a, sWl[k], sbl[k]);
      f = fmaf(fmaxf(hh, 0.f), sWo[k], f);
    }
    int g = batch[i];
    atomicAdd(&ls[g], f);
    atomicAdd(&lc[g], 1.f);
  }
  __syncthreads();
  if (tid < GMAX && lc[tid] != 0.f) {
    atomicAdd(&gsum[tid], ls[tid]);
    atomicAdd(&gcnt[tid], lc[tid]);
  }
}

__global__ void fb_final(const float* __restrict__ gsum,
                         const float* __restrict__ gcnt,
                         const float* __restrict__ b_out,
                         float* __restrict__ out, int G) {
  int g = blockIdx.x * blockDim.x + threadIdx.x;
  if (g < G) out[g] = fmaxf(gsum[g] / fmaxf(gcnt[g], 1.f) + b_out[0], 0.f);
}

// ---------------- launch ----------------

extern "C" void kernel_launch(void* const* d_in, const int* in_sizes, int n_in,
                              void* d_out, int out_size, void* d_ws, size_t ws_size,
                              hipStream_t stream) {
  const float* x     = (const float*)d_in[0];
  const int*   ei    = (const int*)d_in[1];
  const int*   batch = (const int*)d_in[2];
  const float* Wl    = (const float*)d_in[3];
  const float* bl    = (const float*)d_in[4];
  const float* Wo    = (const float*)d_in[5];
  const float* bo    = (const float*)d_in[6];
  float* out = (float*)d_out;

  int N = in_sizes[0];        // 100000
  int E = in_sizes[1] / 2;    // 3200000
  int H = in_sizes[3];        // 256
  int G = out_size;           // 128

  int NB = (N + BS - 1) / BS; // 391
  int Q   = E >> 2;
  int QpB = (Q + SG - 1) / SG;

  // fixed bucket capacity: 2x mean, rounded up to 4096 (multiple of 4)
  int avg = (NB > 0) ? E / NB : 0;
  int CAP = (2 * avg + 4095) & ~4095;
  if (CAP < 4096) CAP = 4096;

  // ws word layout:
  //   cnt [SG*NBMAX] | off [SG*NBMAX] | tot [NBMAX]
  //   gsum[GMAX] | gcnt[GMAX] | done[4] | pairs[NB*CAP]
  const size_t W_MAT = (size_t)SG * NBMAX;
  const size_t HDRW  = 2 * W_MAT + NBMAX + 2 * GMAX + 4;  // 16B-aligned end
  size_t need = (HDRW + (size_t)NB * (size_t)CAP) * 4u;

  unsigned* w = (unsigned*)d_ws;
  if (NB <= NBMAX && ws_size >= need && H <= HMAX && G <= GMAX && G <= 256) {
    unsigned* cnt   = w;
    unsigned* off   = cnt + W_MAT;
    unsigned* tot   = off + W_MAT;
    float*    gsum  = (float*)(tot + NBMAX);
    float*    gcnt  = gsum + GMAX;
    unsigned* done  = (unsigned*)(gcnt + GMAX);
    unsigned* pairs = done + 4;

    s1_count<<<SG, 256, 0, stream>>>(ei, cnt, E, NB, QpB);
    s_scan<<<NB, SG, 0, stream>>>(cnt, off, tot, gsum, gcnt, done);
    s2_scatter<<<SG, 256, 0, stream>>>(ei, off, pairs, E, NB, QpB, CAP);
    s3_reduce<<<NB, 256, 0, stream>>>(pairs, tot, x, batch, Wl, bl, Wo, bo,
                                      gsum, gcnt, done, out, N, H, G, CAP);
  } else {
    float* agg  = (float*)d_ws;
    float* gsum = agg + N;
    float* gcnt = gsum + GMAX;
    hipMemsetAsync(d_ws, 0, ((size_t)N + 2 * GMAX) * 4u, stream);
    fb_scatter<<<(E + 255) / 256, 256, 0, stream>>>(ei, x, agg, E);
    fb_node<<<(N + 255) / 256, 256, 0, stream>>>(agg, batch, Wl, bl, Wo,
                                                 gsum, gcnt, N, H);
    fb_final<<<1, 256, 0, stream>>>(gsum, gcnt, bo, out, G);
  }
}

// Round 6
// 153.637 us; speedup vs baseline: 1.1334x; 1.1334x over previous
//
#include <hip/hip_runtime.h>

// N=100000, E=3200000, H=256, G=128.
// Pipeline (4 kernels): per-block dense histogram -> per-bucket scan ->
// scatter into fixed-capacity buckets -> fused LDS bucket-reduce + collapsed
// MLP f(a)=sum_k relu(a*Wl[k]+bl[k])*Wo[k] + graph mean-pool + epilogue.
// R5 lesson: s3 at 391 blocks x 4 waves = 11.7% occupancy was latency-bound
// (55us); fix = 1024-thread blocks (16 waves) + drop per-block __threadfence.

#define GMAX  128      // max graphs
#define HMAX  256      // max hidden dim
#define BS    256      // nodes per bucket (dst >> 8)
#define NBMAX 512      // max buckets (N <= 131072)
#define SG    1024     // blocks for s1/s2

// ---------------- main path ----------------

// S1: per-block dense histogram of dst buckets; cnt[blk][b] coalesced write.
__global__ __launch_bounds__(256) void s1_count(const int* __restrict__ ei,
                                                unsigned* __restrict__ cnt,
                                                int E, int NB, int QpB) {
  __shared__ unsigned h[NBMAX];
  int tid = threadIdx.x;
  for (int b = tid; b < NB; b += 256) h[b] = 0u;
  __syncthreads();
  int Q = E >> 2;
  int q0 = blockIdx.x * QpB;
  int q1 = min(q0 + QpB, Q);
  const int4* d4 = (const int4*)(ei + E);
  for (int q = q0 + tid; q < q1; q += 256) {
    int4 d = d4[q];
    atomicAdd(&h[d.x >> 8], 1u);
    atomicAdd(&h[d.y >> 8], 1u);
    atomicAdd(&h[d.z >> 8], 1u);
    atomicAdd(&h[d.w >> 8], 1u);
  }
  if (blockIdx.x == 0)   // tail edges (E % 4) counted by block 0
    for (int e = (Q << 2) + tid; e < E; e += 256)
      atomicAdd(&h[ei[E + e] >> 8], 1u);
  __syncthreads();
  for (int b = tid; b < NB; b += 256)
    cnt[(size_t)blockIdx.x * NBMAX + b] = h[b];
}

// Scan: block b scans the SG per-block counts of bucket b, writes off[blk][b]
// + tot[b]. Block 0 also zeros gsum/gcnt/done.
__global__ __launch_bounds__(SG) void s_scan(const unsigned* __restrict__ cnt,
                                             unsigned* __restrict__ off,
                                             unsigned* __restrict__ tot,
                                             float* __restrict__ gsum,
                                             float* __restrict__ gcnt,
                                             unsigned* __restrict__ done) {
  __shared__ unsigned s[SG];
  int b = blockIdx.x, t = threadIdx.x;
  unsigned c = cnt[(size_t)t * NBMAX + b];
  s[t] = c;
  __syncthreads();
  for (int o = 1; o < SG; o <<= 1) {
    unsigned v = (t >= o) ? s[t - o] : 0u;
    __syncthreads();
    s[t] += v;
    __syncthreads();
  }
  off[(size_t)t * NBMAX + b] = s[t] - c;
  if (t == SG - 1) tot[b] = s[t];
  if (b == 0) {
    if (t < GMAX) { gsum[t] = 0.f; gcnt[t] = 0.f; }
    if (t == 0) done[0] = 0u;
  }
}

// S2: scatter edges into fixed-cap buckets (base = b*CAP) at precomputed
// offsets; only LDS rank atomics. pairs[slot] = (src<<8) | (dst & 255).
__global__ __launch_bounds__(256) void s2_scatter(const int* __restrict__ ei,
                                                  const unsigned* __restrict__ off,
                                                  unsigned* __restrict__ pairs,
                                                  int E, int NB, int QpB, int CAP) {
  __shared__ unsigned hb[NBMAX];    // my block's write base per bucket
  __shared__ unsigned rcur[NBMAX];  // local running rank
  int tid = threadIdx.x;
  for (int b = tid; b < NB; b += 256) {
    hb[b] = (unsigned)b * (unsigned)CAP + off[(size_t)blockIdx.x * NBMAX + b];
    rcur[b] = 0u;
  }
  __syncthreads();
  int Q = E >> 2;
  int q0 = blockIdx.x * QpB;
  int q1 = min(q0 + QpB, Q);
  const int4* s4 = (const int4*)ei;
  const int4* d4 = (const int4*)(ei + E);
  unsigned capu = (unsigned)CAP;
  for (int q = q0 + tid; q < q1; q += 256) {
    int4 s = s4[q];
    int4 d = d4[q];
    { int b = d.x >> 8; unsigned r = atomicAdd(&rcur[b], 1u);
      unsigned slot = hb[b] + r;
      if (slot < (unsigned)(b + 1) * capu)   // clamp: never corrupt neighbors
        pairs[slot] = ((unsigned)s.x << 8) | (unsigned)(d.x & 255); }
    { int b = d.y >> 8; unsigned r = atomicAdd(&rcur[b], 1u);
      unsigned slot = hb[b] + r;
      if (slot < (unsigned)(b + 1) * capu)
        pairs[slot] = ((unsigned)s.y << 8) | (unsigned)(d.y & 255); }
    { int b = d.z >> 8; unsigned r = atomicAdd(&rcur[b], 1u);
      unsigned slot = hb[b] + r;
      if (slot < (unsigned)(b + 1) * capu)
        pairs[slot] = ((unsigned)s.z << 8) | (unsigned)(d.z & 255); }
    { int b = d.w >> 8; unsigned r = atomicAdd(&rcur[b], 1u);
      unsigned slot = hb[b] + r;
      if (slot < (unsigned)(b + 1) * capu)
        pairs[slot] = ((unsigned)s.w << 8) | (unsigned)(d.w & 255); }
  }
  if (blockIdx.x == 0)   // tail edges, matching s1_count
    for (int e = (Q << 2) + tid; e < E; e += 256) {
      int d = ei[E + e], s = ei[e];
      int b = d >> 8; unsigned r = atomicAdd(&rcur[b], 1u);
      unsigned slot = hb[b] + r;
      if (slot < (unsigned)(b + 1) * capu)
        pairs[slot] = ((unsigned)s << 8) | (unsigned)(d & 255);
    }
}

// S3 (fused): bucket reduce in LDS -> per-node f(a) -> per-graph pooling;
// the last block to finish applies the final epilogue.
// 1024 threads/block (16 waves) for latency hiding of the gather chain.
__global__ __launch_bounds__(1024) void s3_reduce(
    const unsigned* __restrict__ pairs, const unsigned* __restrict__ tot,
    const float* __restrict__ x, const int* __restrict__ batch,
    const float* __restrict__ Wl, const float* __restrict__ bl,
    const float* __restrict__ Wo, const float* __restrict__ b_out,
    float* __restrict__ gsum, float* __restrict__ gcnt,
    unsigned* __restrict__ done, float* __restrict__ out,
    int N, int H, int G, int CAP) {
  __shared__ float acc[BS];
  __shared__ float sWl[HMAX], sbl[HMAX], sWo[HMAX];
  __shared__ float ls[GMAX], lc[GMAX];
  __shared__ unsigned ticket;
  int tid = threadIdx.x, b = blockIdx.x;
  if (tid < BS) acc[tid] = 0.f;
  if (tid < H) { sWl[tid] = Wl[tid]; sbl[tid] = bl[tid]; sWo[tid] = Wo[tid]; }
  if (tid < GMAX) { ls[tid] = 0.f; lc[tid] = 0.f; }
  __syncthreads();

  unsigned lo = (unsigned)b * (unsigned)CAP;
  unsigned cnt = min(tot[b], (unsigned)CAP);
  unsigned q4 = cnt >> 2;
  const uint4* p4 = (const uint4*)(pairs + lo);   // CAP%4==0 -> 16B aligned
  for (unsigned i = tid; i < q4; i += 1024) {
    uint4 p = p4[i];
    atomicAdd(&acc[p.x & 255u], x[p.x >> 8]);
    atomicAdd(&acc[p.y & 255u], x[p.y >> 8]);
    atomicAdd(&acc[p.z & 255u], x[p.z >> 8]);
    atomicAdd(&acc[p.w & 255u], x[p.w >> 8]);
  }
  if (tid < (int)(cnt & 3u)) {
    unsigned p = pairs[lo + (q4 << 2) + tid];
    atomicAdd(&acc[p & 255u], x[p >> 8]);
  }
  __syncthreads();

  int node = b * BS + tid;
  if (tid < BS && node < N) {
    float a = acc[tid], f = 0.f;
#pragma unroll 8
    for (int k = 0; k < H; ++k) {
      float hh = fmaf(a, sWl[k], sbl[k]);
      f = fmaf(fmaxf(hh, 0.f), sWo[k], f);
    }
    int g = batch[node];
    atomicAdd(&ls[g], f);
    atomicAdd(&lc[g], 1.f);
  }
  __syncthreads();
  if (tid < GMAX && lc[tid] != 0.f) {
    atomicAdd(&gsum[tid], ls[tid]);   // device-scope, memory-side
    atomicAdd(&gcnt[tid], lc[tid]);
  }
  __syncthreads();
  // epilogue: last block to finish computes out[g]. ACQ_REL orders my gsum
  // atomics before the ticket without a full __threadfence.
  if (tid == 0)
    ticket = __hip_atomic_fetch_add(done, 1u, __ATOMIC_ACQ_REL,
                                    __HIP_MEMORY_SCOPE_AGENT);
  __syncthreads();
  if (ticket == gridDim.x - 1 && tid < G) {
    float s = __hip_atomic_load(&gsum[tid], __ATOMIC_RELAXED, __HIP_MEMORY_SCOPE_AGENT);
    float c = __hip_atomic_load(&gcnt[tid], __ATOMIC_RELAXED, __HIP_MEMORY_SCOPE_AGENT);
    out[tid] = fmaxf(s / fmaxf(c, 1.f) + b_out[0], 0.f);
  }
}

// ---------------- fallback path (small ws or oversized N) ----------------

__global__ __launch_bounds__(256) void fb_scatter(const int* __restrict__ ei,
                                                  const float* __restrict__ x,
                                                  float* __restrict__ agg, int E) {
  int t = blockIdx.x * blockDim.x + threadIdx.x;
  if (t < E) atomicAdd(&agg[ei[E + t]], x[ei[t]]);
}

__global__ __launch_bounds__(256) void fb_node(const float* __restrict__ agg,
                                               const int* __restrict__ batch,
                                               const float* __restrict__ Wl,
                                               const float* __restrict__ bl,
                                               const float* __restrict__ Wo,
                                               float* __restrict__ gsum,
                                               float* __restrict__ gcnt, int N, int H) {
  __shared__ float sWl[HMAX], sbl[HMAX], sWo[HMAX];
  __shared__ float ls[GMAX], lc[GMAX];
  int tid = threadIdx.x;
  if (tid < H) { sWl[tid] = Wl[tid]; sbl[tid] = bl[tid]; sWo[tid] = Wo[tid]; }
  if (tid < GMAX) { ls[tid] = 0.f; lc[tid] = 0.f; }
  __syncthreads();
  int i = blockIdx.x * blockDim.x + tid;
  if (i < N) {
    float a = agg[i], f = 0.f;
    for (int k = 0; k < H; ++k) {
      float hh = fmaf(a, sWl[k], sbl[k]);
      f = fmaf(fmaxf(hh, 0.f), sWo[k], f);
    }
    int g = batch[i];
    atomicAdd(&ls[g], f);
    atomicAdd(&lc[g], 1.f);
  }
  __syncthreads();
  if (tid < GMAX && lc[tid] != 0.f) {
    atomicAdd(&gsum[tid], ls[tid]);
    atomicAdd(&gcnt[tid], lc[tid]);
  }
}

__global__ void fb_final(const float* __restrict__ gsum,
                         const float* __restrict__ gcnt,
                         const float* __restrict__ b_out,
                         float* __restrict__ out, int G) {
  int g = blockIdx.x * blockDim.x + threadIdx.x;
  if (g < G) out[g] = fmaxf(gsum[g] / fmaxf(gcnt[g], 1.f) + b_out[0], 0.f);
}

// ---------------- launch ----------------

extern "C" void kernel_launch(void* const* d_in, const int* in_sizes, int n_in,
                              void* d_out, int out_size, void* d_ws, size_t ws_size,
                              hipStream_t stream) {
  const float* x     = (const float*)d_in[0];
  const int*   ei    = (const int*)d_in[1];
  const int*   batch = (const int*)d_in[2];
  const float* Wl    = (const float*)d_in[3];
  const float* bl    = (const float*)d_in[4];
  const float* Wo    = (const float*)d_in[5];
  const float* bo    = (const float*)d_in[6];
  float* out = (float*)d_out;

  int N = in_sizes[0];        // 100000
  int E = in_sizes[1] / 2;    // 3200000
  int H = in_sizes[3];        // 256
  int G = out_size;           // 128

  int NB = (N + BS - 1) / BS; // 391
  int Q   = E >> 2;
  int QpB = (Q + SG - 1) / SG;

  // fixed bucket capacity: 2x mean, rounded up to 4096 (multiple of 4)
  int avg = (NB > 0) ? E / NB : 0;
  int CAP = (2 * avg + 4095) & ~4095;
  if (CAP < 4096) CAP = 4096;

  // ws word layout:
  //   cnt [SG*NBMAX] | off [SG*NBMAX] | tot [NBMAX]
  //   gsum[GMAX] | gcnt[GMAX] | done[4] | pairs[NB*CAP]
  const size_t W_MAT = (size_t)SG * NBMAX;
  const size_t HDRW  = 2 * W_MAT + NBMAX + 2 * GMAX + 4;  // 16B-aligned end
  size_t need = (HDRW + (size_t)NB * (size_t)CAP) * 4u;

  unsigned* w = (unsigned*)d_ws;
  if (NB <= NBMAX && ws_size >= need && H <= HMAX && G <= GMAX) {
    unsigned* cnt   = w;
    unsigned* off   = cnt + W_MAT;
    unsigned* tot   = off + W_MAT;
    float*    gsum  = (float*)(tot + NBMAX);
    float*    gcnt  = gsum + GMAX;
    unsigned* done  = (unsigned*)(gcnt + GMAX);
    unsigned* pairs = done + 4;

    s1_count<<<SG, 256, 0, stream>>>(ei, cnt, E, NB, QpB);
    s_scan<<<NB, SG, 0, stream>>>(cnt, off, tot, gsum, gcnt, done);
    s2_scatter<<<SG, 256, 0, stream>>>(ei, off, pairs, E, NB, QpB, CAP);
    s3_reduce<<<NB, 1024, 0, stream>>>(pairs, tot, x, batch, Wl, bl, Wo, bo,
                                       gsum, gcnt, done, out, N, H, G, CAP);
  } else {
    float* agg  = (float*)d_ws;
    float* gsum = agg + N;
    float* gcnt = gsum + GMAX;
    hipMemsetAsync(d_ws, 0, ((size_t)N + 2 * GMAX) * 4u, stream);
    fb_scatter<<<(E + 255) / 256, 256, 0, stream>>>(ei, x, agg, E);
    fb_node<<<(N + 255) / 256, 256, 0, stream>>>(agg, batch, Wl, bl, Wo,
                                                 gsum, gcnt, N, H);
    fb_final<<<1, 256, 0, stream>>>(gsum, gcnt, bo, out, G);
  }
}

// Round 7
// 130.459 us; speedup vs baseline: 1.3348x; 1.1777x over previous
//
#include <hip/hip_runtime.h>

// N=100000, E=3200000, H=256, G=128.
// Pipeline (4 kernels): s1 per-block dense histogram -> s_scan per-bucket
// cross-block offsets -> s2 block-local LDS counting-sort + coalesced write
// into fixed-capacity buckets -> s3 fused LDS bucket-reduce + collapsed MLP
// f(a)=sum_k relu(a*Wl[k]+bl[k])*Wo[k] + graph mean-pool + ticket epilogue.
// R6 lesson: scattered 4B stores in s2 -> WRITE_SIZE 64MB (5x amplification).
// Fix: sort the block's edges in LDS first, write runs (~16 words) coalesced.

#define GMAX  128      // max graphs
#define HMAX  256      // max hidden dim
#define BS    256      // nodes per bucket (dst >> 8)
#define NBMAX 512      // max buckets (N <= 131072)
#define SG    512      // blocks for s1/s2 (and scan width)
#define BLK2  512      // threads per s2 block
#define CEDGE 6400     // LDS sort capacity per block (>= QpB*4 + 4)

// ---------------- main path ----------------

// S1: per-block dense histogram of dst buckets; cnt[blk][b] coalesced write.
__global__ __launch_bounds__(256) void s1_count(const int* __restrict__ ei,
                                                unsigned* __restrict__ cnt,
                                                int E, int NB, int QpB) {
  __shared__ unsigned h[NBMAX];
  int tid = threadIdx.x;
  for (int b = tid; b < NB; b += 256) h[b] = 0u;
  __syncthreads();
  int Q = E >> 2;
  int q0 = blockIdx.x * QpB;
  int q1 = min(q0 + QpB, Q);
  const int4* d4 = (const int4*)(ei + E);
  for (int q = q0 + tid; q < q1; q += 256) {
    int4 d = d4[q];
    atomicAdd(&h[d.x >> 8], 1u);
    atomicAdd(&h[d.y >> 8], 1u);
    atomicAdd(&h[d.z >> 8], 1u);
    atomicAdd(&h[d.w >> 8], 1u);
  }
  if (blockIdx.x == 0)   // tail edges (E % 4) counted by block 0
    for (int e = (Q << 2) + tid; e < E; e += 256)
      atomicAdd(&h[ei[E + e] >> 8], 1u);
  __syncthreads();
  for (int b = tid; b < NB; b += 256)
    cnt[(size_t)blockIdx.x * NBMAX + b] = h[b];
}

// Scan: block b scans the SG per-block counts of bucket b, writes off[blk][b]
// + tot[b]. Block 0 also zeros gsum/gcnt/done.
__global__ __launch_bounds__(SG) void s_scan(const unsigned* __restrict__ cnt,
                                             unsigned* __restrict__ off,
                                             unsigned* __restrict__ tot,
                                             float* __restrict__ gsum,
                                             float* __restrict__ gcnt,
                                             unsigned* __restrict__ done) {
  __shared__ unsigned s[SG];
  int b = blockIdx.x, t = threadIdx.x;
  unsigned c = cnt[(size_t)t * NBMAX + b];
  s[t] = c;
  __syncthreads();
  for (int o = 1; o < SG; o <<= 1) {
    unsigned v = (t >= o) ? s[t - o] : 0u;
    __syncthreads();
    s[t] += v;
    __syncthreads();
  }
  off[(size_t)t * NBMAX + b] = s[t] - c;
  if (t == SG - 1) tot[b] = s[t];
  if (b == 0) {
    if (t < GMAX) { gsum[t] = 0.f; gcnt[t] = 0.f; }
    if (t == 0) done[0] = 0u;
  }
}

// S2: block-local counting sort in LDS, then coalesced write to fixed-cap
// buckets (base = b*CAP + off[blk][b]). pairs[slot] = (src<<8) | (dst&255).
__global__ __launch_bounds__(BLK2) void s2_scatter(const int* __restrict__ ei,
                                                   const unsigned* __restrict__ cnt,
                                                   const unsigned* __restrict__ off,
                                                   unsigned* __restrict__ pairs,
                                                   int E, int NB, int QpB, int CAP) {
  __shared__ unsigned lp[CEDGE];        // sorted pairs
  __shared__ unsigned short lb[CEDGE];  // bucket id per sorted slot
  __shared__ unsigned lbase[NBMAX];     // block-local bucket base (excl scan)
  __shared__ unsigned lrank[NBMAX];     // running rank
  __shared__ unsigned hb[NBMAX];        // global write base per bucket
  __shared__ unsigned sc[NBMAX];        // scan temp
  int tid = threadIdx.x, blk = blockIdx.x;

  // load my cnt row, global base; local exclusive scan over buckets
  for (int b = tid; b < NBMAX; b += BLK2) {
    unsigned c = (b < NB) ? cnt[(size_t)blk * NBMAX + b] : 0u;
    sc[b] = c;
    lrank[b] = 0u;
    if (b < NB) hb[b] = (unsigned)b * (unsigned)CAP + off[(size_t)blk * NBMAX + b];
  }
  __syncthreads();
  // Hillis-Steele inclusive scan over NBMAX entries (NBMAX <= BLK2)
  for (int o = 1; o < NBMAX; o <<= 1) {
    unsigned v = 0u;
    if (tid < NBMAX && tid >= o) v = sc[tid - o];
    __syncthreads();
    if (tid < NBMAX) sc[tid] += v;
    __syncthreads();
  }
  for (int b = tid; b < NB; b += BLK2) {
    unsigned c = cnt[(size_t)blk * NBMAX + b];
    lbase[b] = sc[b] - c;    // exclusive
  }
  __syncthreads();

  // placement: one pass over my edges into sorted LDS position
  int Q = E >> 2;
  int q0 = blk * QpB;
  int q1 = min(q0 + QpB, Q);
  const int4* s4 = (const int4*)ei;
  const int4* d4 = (const int4*)(ei + E);
  for (int q = q0 + tid; q < q1; q += BLK2) {
    int4 s = s4[q];
    int4 d = d4[q];
    { int b = d.x >> 8; unsigned r = atomicAdd(&lrank[b], 1u);
      unsigned p = lbase[b] + r;
      lp[p] = ((unsigned)s.x << 8) | (unsigned)(d.x & 255); lb[p] = (unsigned short)b; }
    { int b = d.y >> 8; unsigned r = atomicAdd(&lrank[b], 1u);
      unsigned p = lbase[b] + r;
      lp[p] = ((unsigned)s.y << 8) | (unsigned)(d.y & 255); lb[p] = (unsigned short)b; }
    { int b = d.z >> 8; unsigned r = atomicAdd(&lrank[b], 1u);
      unsigned p = lbase[b] + r;
      lp[p] = ((unsigned)s.z << 8) | (unsigned)(d.z & 255); lb[p] = (unsigned short)b; }
    { int b = d.w >> 8; unsigned r = atomicAdd(&lrank[b], 1u);
      unsigned p = lbase[b] + r;
      lp[p] = ((unsigned)s.w << 8) | (unsigned)(d.w & 255); lb[p] = (unsigned short)b; }
  }
  int total = (q1 - q0) * 4;
  if (blk == 0) {            // tail edges (E % 4)
    for (int e = (Q << 2) + tid; e < E; e += BLK2) {
      int d = ei[E + e], s = ei[e];
      int b = d >> 8; unsigned r = atomicAdd(&lrank[b], 1u);
      unsigned p = lbase[b] + r;
      lp[p] = ((unsigned)s << 8) | (unsigned)(d & 255); lb[p] = (unsigned short)b;
    }
    total += (E & 3);
  }
  if (total > CEDGE) total = CEDGE;   // safety (host gates this anyway)
  __syncthreads();

  // writeout: consecutive i -> consecutive slots within bucket runs (~16 words)
  unsigned capu = (unsigned)CAP;
  for (int i = tid; i < total; i += BLK2) {
    unsigned b = lb[i];
    unsigned slot = hb[b] + ((unsigned)i - lbase[b]);
    if (slot < (b + 1u) * capu)       // clamp: never corrupt neighbors
      pairs[slot] = lp[i];
  }
}

// S3 (fused): bucket reduce in LDS -> per-node f(a) -> per-graph pooling;
// last-finishing block applies the final epilogue (device-scope ticket).
__global__ __launch_bounds__(1024) void s3_reduce(
    const unsigned* __restrict__ pairs, const unsigned* __restrict__ tot,
    const float* __restrict__ x, const int* __restrict__ batch,
    const float* __restrict__ Wl, const float* __restrict__ bl,
    const float* __restrict__ Wo, const float* __restrict__ b_out,
    float* __restrict__ gsum, float* __restrict__ gcnt,
    unsigned* __restrict__ done, float* __restrict__ out,
    int N, int H, int G, int CAP) {
  __shared__ float acc[BS];
  __shared__ float sWl[HMAX], sbl[HMAX], sWo[HMAX];
  __shared__ float ls[GMAX], lc[GMAX];
  __shared__ unsigned ticket;
  int tid = threadIdx.x, b = blockIdx.x;
  if (tid < BS) acc[tid] = 0.f;
  if (tid < H) { sWl[tid] = Wl[tid]; sbl[tid] = bl[tid]; sWo[tid] = Wo[tid]; }
  if (tid < GMAX) { ls[tid] = 0.f; lc[tid] = 0.f; }
  __syncthreads();

  unsigned lo = (unsigned)b * (unsigned)CAP;
  unsigned cnt = min(tot[b], (unsigned)CAP);
  unsigned q4 = cnt >> 2;
  const uint4* p4 = (const uint4*)(pairs + lo);   // CAP%4==0 -> 16B aligned
  for (unsigned i = tid; i < q4; i += 1024) {
    uint4 p = p4[i];
    atomicAdd(&acc[p.x & 255u], x[p.x >> 8]);
    atomicAdd(&acc[p.y & 255u], x[p.y >> 8]);
    atomicAdd(&acc[p.z & 255u], x[p.z >> 8]);
    atomicAdd(&acc[p.w & 255u], x[p.w >> 8]);
  }
  if (tid < (int)(cnt & 3u)) {
    unsigned p = pairs[lo + (q4 << 2) + tid];
    atomicAdd(&acc[p & 255u], x[p >> 8]);
  }
  __syncthreads();

  int node = b * BS + tid;
  if (tid < BS && node < N) {
    float a = acc[tid], f = 0.f;
#pragma unroll 8
    for (int k = 0; k < H; ++k) {
      float hh = fmaf(a, sWl[k], sbl[k]);
      f = fmaf(fmaxf(hh, 0.f), sWo[k], f);
    }
    int g = batch[node];
    atomicAdd(&ls[g], f);
    atomicAdd(&lc[g], 1.f);
  }
  __syncthreads();
  if (tid < GMAX && lc[tid] != 0.f) {
    atomicAdd(&gsum[tid], ls[tid]);   // device-scope, memory-side
    atomicAdd(&gcnt[tid], lc[tid]);
  }
  __syncthreads();
  if (tid == 0)
    ticket = __hip_atomic_fetch_add(done, 1u, __ATOMIC_ACQ_REL,
                                    __HIP_MEMORY_SCOPE_AGENT);
  __syncthreads();
  if (ticket == gridDim.x - 1 && tid < G) {
    float s = __hip_atomic_load(&gsum[tid], __ATOMIC_RELAXED, __HIP_MEMORY_SCOPE_AGENT);
    float c = __hip_atomic_load(&gcnt[tid], __ATOMIC_RELAXED, __HIP_MEMORY_SCOPE_AGENT);
    out[tid] = fmaxf(s / fmaxf(c, 1.f) + b_out[0], 0.f);
  }
}

// ---------------- fallback path (small ws or oversized N) ----------------

__global__ __launch_bounds__(256) void fb_scatter(const int* __restrict__ ei,
                                                  const float* __restrict__ x,
                                                  float* __restrict__ agg, int E) {
  int t = blockIdx.x * blockDim.x + threadIdx.x;
  if (t < E) atomicAdd(&agg[ei[E + t]], x[ei[t]]);
}

__global__ __launch_bounds__(256) void fb_node(const float* __restrict__ agg,
                                               const int* __restrict__ batch,
                                               const float* __restrict__ Wl,
                                               const float* __restrict__ bl,
                                               const float* __restrict__ Wo,
                                               float* __restrict__ gsum,
                                               float* __restrict__ gcnt, int N, int H) {
  __shared__ float sWl[HMAX], sbl[HMAX], sWo[HMAX];
  __shared__ float ls[GMAX], lc[GMAX];
  int tid = threadIdx.x;
  if (tid < H) { sWl[tid] = Wl[tid]; sbl[tid] = bl[tid]; sWo[tid] = Wo[tid]; }
  if (tid < GMAX) { ls[tid] = 0.f; lc[tid] = 0.f; }
  __syncthreads();
  int i = blockIdx.x * blockDim.x + tid;
  if (i < N) {
    float a = agg[i], f = 0.f;
    for (int k = 0; k < H; ++k) {
      float hh = fmaf(a, sWl[k], sbl[k]);
      f = fmaf(fmaxf(hh, 0.f), sWo[k], f);
    }
    int g = batch[i];
    atomicAdd(&ls[g], f);
    atomicAdd(&lc[g], 1.f);
  }
  __syncthreads();
  if (tid < GMAX && lc[tid] != 0.f) {
    atomicAdd(&gsum[tid], ls[tid]);
    atomicAdd(&gcnt[tid], lc[tid]);
  }
}

__global__ void fb_final(const float* __restrict__ gsum,
                         const float* __restrict__ gcnt,
                         const float* __restrict__ b_out,
                         float* __restrict__ out, int G) {
  int g = blockIdx.x * blockDim.x + threadIdx.x;
  if (g < G) out[g] = fmaxf(gsum[g] / fmaxf(gcnt[g], 1.f) + b_out[0], 0.f);
}

// ---------------- launch ----------------

extern "C" void kernel_launch(void* const* d_in, const int* in_sizes, int n_in,
                              void* d_out, int out_size, void* d_ws, size_t ws_size,
                              hipStream_t stream) {
  const float* x     = (const float*)d_in[0];
  const int*   ei    = (const int*)d_in[1];
  const int*   batch = (const int*)d_in[2];
  const float* Wl    = (const float*)d_in[3];
  const float* bl    = (const float*)d_in[4];
  const float* Wo    = (const float*)d_in[5];
  const float* bo    = (const float*)d_in[6];
  float* out = (float*)d_out;

  int N = in_sizes[0];        // 100000
  int E = in_sizes[1] / 2;    // 3200000
  int H = in_sizes[3];        // 256
  int G = out_size;           // 128

  int NB = (N + BS - 1) / BS; // 391
  int Q   = E >> 2;
  int QpB = (Q + SG - 1) / SG;

  // fixed bucket capacity: 2x mean, rounded up to 4096 (multiple of 4)
  int avg = (NB > 0) ? E / NB : 0;
  int CAP = (2 * avg + 4095) & ~4095;
  if (CAP < 4096) CAP = 4096;

  // ws word layout:
  //   cnt [SG*NBMAX] | off [SG*NBMAX] | tot [NBMAX]
  //   gsum[GMAX] | gcnt[GMAX] | done[4] | pairs[NB*CAP]
  const size_t W_MAT = (size_t)SG * NBMAX;
  const size_t HDRW  = 2 * W_MAT + NBMAX + 2 * GMAX + 4;  // 16B-aligned end
  size_t need = (HDRW + (size_t)NB * (size_t)CAP) * 4u;

  unsigned* w = (unsigned*)d_ws;
  if (NB <= NBMAX && ws_size >= need && H <= HMAX && G <= GMAX &&
      QpB * 4 + 4 <= CEDGE) {
    unsigned* cnt   = w;
    unsigned* off   = cnt + W_MAT;
    unsigned* tot   = off + W_MAT;
    float*    gsum  = (float*)(tot + NBMAX);
    float*    gcnt  = gsum + GMAX;
    unsigned* done  = (unsigned*)(gcnt + GMAX);
    unsigned* pairs = done + 4;

    s1_count<<<SG, 256, 0, stream>>>(ei, cnt, E, NB, QpB);
    s_scan<<<NB, SG, 0, stream>>>(cnt, off, tot, gsum, gcnt, done);
    s2_scatter<<<SG, BLK2, 0, stream>>>(ei, cnt, off, pairs, E, NB, QpB, CAP);
    s3_reduce<<<NB, 1024, 0, stream>>>(pairs, tot, x, batch, Wl, bl, Wo, bo,
                                       gsum, gcnt, done, out, N, H, G, CAP);
  } else {
    float* agg  = (float*)d_ws;
    float* gsum = agg + N;
    float* gcnt = gsum + GMAX;
    hipMemsetAsync(d_ws, 0, ((size_t)N + 2 * GMAX) * 4u, stream);
    fb_scatter<<<(E + 255) / 256, 256, 0, stream>>>(ei, x, agg, E);
    fb_node<<<(N + 255) / 256, 256, 0, stream>>>(agg, batch, Wl, bl, Wo,
                                                 gsum, gcnt, N, H);
    fb_final<<<1, 256, 0, stream>>>(gsum, gcnt, bo, out, G);
  }
}